// Round 18
// baseline (753.852 us; speedup 1.0000x reference)
//
#include <hip/hip_runtime.h>
#include <hip/hip_bf16.h>
#include <stdint.h>

typedef __attribute__((ext_vector_type(8))) short short8;
typedef __attribute__((ext_vector_type(8))) unsigned short ushort8;
typedef __attribute__((ext_vector_type(4))) float f32x4;
typedef __attribute__((ext_vector_type(8))) __bf16 bf16x8;

#define GAS __attribute__((address_space(1)))
#define LAS __attribute__((address_space(3)))

static constexpr int Bn = 16384;   // batch
static constexpr int Hn = 1024;    // hidden
static constexpr int KT = 4096;    // IN + H + CTX (concat K)
static constexpr int NT = KT / 64; // 64 K-tiles

#define SBAR()   __builtin_amdgcn_s_barrier()
#define VMCNT(n) asm volatile("s_waitcnt vmcnt(" #n ")" ::: "memory")
#define FENCE()  asm volatile("" ::: "memory")

__device__ __forceinline__ unsigned short f2bf(float f) {
  unsigned u = __builtin_bit_cast(unsigned, f);
  u = (u + 0x7FFFu + ((u >> 16) & 1u)) >> 16;   // RNE
  return (unsigned short)u;
}

__device__ __forceinline__ float fast_sigm(float x) {
  return __builtin_amdgcn_rcpf(1.f + __expf(-x));
}
__device__ __forceinline__ float fast_tanh(float x) {
  return 1.f - 2.f * __builtin_amdgcn_rcpf(__expf(2.f * x) + 1.f);
}

// Pack X (y|h0|ctx) into A-frag-major records for 16x16x32 MFMA.
// Record (mb 0..1023, k32 0..127) at byte (mb*128 + k32)*1024 + lane*16.
// Lane l: row = mb*16 + (l&15), k = k32*32 + (l>>4)*8  (matches the A-operand
// lane map row=lane&15, k-octet=lane>>4 used by r10's verified LDS reads).
// Reads: wave = 16 rows x 128B contiguous segments (fully consumed);
// writes lane-consecutive (coalesced). k32-fast rec order -> streaming.
__global__ __launch_bounds__(256) void cvt_pack_x(
    const float* __restrict__ s0, const float* __restrict__ s1,
    const float* __restrict__ s2, unsigned short* __restrict__ dst,
    long long ntot) {
  long long stride = (long long)gridDim.x * blockDim.x;
  for (long long g = (long long)blockIdx.x * blockDim.x + threadIdx.x; g < ntot;
       g += stride) {
    int l = (int)(g & 63);
    long long rec = g >> 6;
    int k32 = (int)(rec & 127);
    int mb = (int)(rec >> 7);
    int row = mb * 16 + (l & 15);
    int k0 = k32 * 32 + ((l >> 4) << 3);
    const float* src;
    if (k0 < 1024)      src = s0 + (size_t)row * 1024 + k0;
    else if (k0 < 2048) src = s1 + (size_t)row * 1024 + (k0 - 1024);
    else                src = s2 + (size_t)row * 2048 + (k0 - 2048);
    float4 f0 = *(const float4*)src;
    float4 f1 = *(const float4*)(src + 4);
    ushort8 o;
    o[0] = f2bf(f0.x); o[1] = f2bf(f0.y); o[2] = f2bf(f0.z); o[3] = f2bf(f0.w);
    o[4] = f2bf(f1.x); o[5] = f2bf(f1.y); o[6] = f2bf(f1.z); o[7] = f2bf(f1.w);
    *(ushort8*)(dst + (g << 3)) = o;
  }
}

// Pack W|U|C into 16x16x32-MFMA B-frag records — WRITE-COALESCED (r10).
__global__ __launch_bounds__(256) void cvt_pack_w(
    const float* __restrict__ s0, const float* __restrict__ s1,
    const float* __restrict__ s2, unsigned short* __restrict__ dst,
    long long ntot) {
  long long stride = (long long)gridDim.x * blockDim.x;
  for (long long g = (long long)blockIdx.x * blockDim.x + threadIdx.x; g < ntot;
       g += stride) {
    int li = (int)(g & 63);
    long long rec = g >> 6;
    int cb = (int)(rec & 255);
    int k32 = (int)(rec >> 8);
    int fr = li & 15, ksl = li >> 4;
    int row = cb * 16 + fr;            // W-concat row = gemm column
    int k0 = k32 * 32 + ksl * 8;
    const float* src;
    if (k0 < 1024)      src = s0 + (size_t)row * 1024 + k0;
    else if (k0 < 2048) src = s1 + (size_t)row * 1024 + (k0 - 1024);
    else                src = s2 + (size_t)row * 2048 + (k0 - 2048);
    float4 f0 = *(const float4*)src;
    float4 f1 = *(const float4*)(src + 4);
    ushort8 o;
    o[0] = f2bf(f0.x); o[1] = f2bf(f0.y); o[2] = f2bf(f0.z); o[3] = f2bf(f0.w);
    o[4] = f2bf(f1.x); o[5] = f2bf(f1.y); o[6] = f2bf(f1.z); o[7] = f2bf(f1.w);
    *(ushort8*)(dst + (g << 3)) = o;
  }
}

// 256x256 GEMM + fused LSTM. 16x16x32 MFMA, 8 waves (2M x 4N).
// r18 ROLE SWAP vs r10: B (weights) -> LDS, A (activations) -> direct global.
// Rationale (measured): r10's pipes SUM (MFMA 2390 + LDS 1540 cyc/tile).
// LDS traffic ∝ 1/wave_cols for the LDS operand; A in LDS = 4x amplification
// (128KB/tile). B in LDS = 2x-equivalent: stage 32KB/tile, waves read their
// 8 B-frags ONCE per tile (64KB reads) -> LDS 160->96 KB/tile and the per-q
// LDS chatter disappears. A-frags come frag-major from global (cvt_pack_x),
// L2-served (A panel 2MB shared by 16 same-XCD blocks), one-q-ahead into
// ping-pong register sets (arE/arO, static indices) -> latency hidden by
// register-dependency waits under MFMAs, no lgkm barriers.
// Ledger (in-order VMEM; 20/wave/tile = 4 A-loads x4q + 4 B-DMA @q3):
//   gate at tile end = VMCNT(24): after B(t+1)-DMA (issued t-1 q3) come
//   4 A(t,q0) + tile t's 20 = 24 ops -> retires exactly B(t+1). Prologue
//   gate VMCNT(8) (B(0) + 8 younger). Never vmcnt(0) mid-loop.
__global__ __launch_bounds__(512, 2) void lstm_gemm(
    const unsigned short* __restrict__ Xp, const unsigned short* __restrict__ Wp,
    const float* __restrict__ bias, const float* __restrict__ c0,
    float* __restrict__ out_c, float* __restrict__ out_h) {
  extern __shared__ char smem[];  // 3 x 32KB B buffers (32 records each)

  int bid = blockIdx.x;
  int swz = (bid & 7) * 128 + (bid >> 3);  // 1024 blocks, 8 XCDs, bijective
  int mblk = swz >> 4, cblk = swz & 15;    // 16 consecutive share A-panel
  int brow0 = mblk * 256;
  int hcol0 = cblk * 64;

  int tid = threadIdx.x;
  int lane = tid & 63, wid = tid >> 6;
  int wr = wid >> 2, wc = wid & 3;  // 2M x 4N wave grid

  const char* Xc = (const char*)Xp;
  const char* Wpc = (const char*)Wp;
  int fr = lane & 15;

  // ---- A record base offsets: ab[q*2+s] for m-frag (q,s) of this wave ----
  uint32_t ab[8];
#pragma unroll
  for (int q = 0; q < 4; ++q)
#pragma unroll
    for (int s = 0; s < 2; ++s) {
      int mb = mblk * 16 + (2 * q + wr) * 2 + s;
      ab[q * 2 + s] = (uint32_t)mb * 131072u + (uint32_t)(lane << 4);
    }

  // ---- B staging: wave stages records fi = wid*4+jj (fi = n*8 + w*2 + ks) --
  auto stage_B = [&](int tt, int dbuf) {
    int ts = tt < NT ? tt : NT - 1;
#pragma unroll
    for (int jj = 0; jj < 4; ++jj) {
      int fi = wid * 4 + jj;
      int n = fi >> 3, w = (fi >> 1) & 3, ks = fi & 1;
      int cb = n * 64 + cblk * 4 + w;
      int k32 = 2 * ts + ks;
      const char* src = Wpc + ((size_t)k32 * 256 + cb) * 1024 + (lane << 4);
      char* dst = smem + dbuf * 32768 + fi * 1024;
      __builtin_amdgcn_global_load_lds((const GAS unsigned int*)src,
                                       (LAS unsigned int*)dst, 16, 0, 0);
    }
  };

  f32x4 acc[8][4] = {};
  short8 bfr[4][2];            // B frags [n][k-slice], refreshed each tile
  short8 arE[4], arO[4];       // A ping-pong sets [s*2+ks]

  // ---- prologue: B(0)->buf0, B(1)->buf1; A(0,q0)->arE; gate B(0) ----
  stage_B(0, 0);
  stage_B(1, 1);
  FENCE();
  {
    arE[0] = *(const short8*)(Xc + ab[0]);
    arE[1] = *(const short8*)(Xc + ab[0] + 1024);
    arE[2] = *(const short8*)(Xc + ab[1]);
    arE[3] = *(const short8*)(Xc + ab[1] + 1024);
  }
  VMCNT(8);   // retire B(0); B(1) + A stay in flight
  SBAR();

  int bufB = 0;

#define PHASE(Q_, CUR, NXT)                                                   \
  {                                                                           \
    if ((Q_) < 3) {  /* read A(t, Q_+1) -> NXT */                             \
      uint32_t ko = (uint32_t)(2 * t) << 10;                                  \
      NXT[0] = *(const short8*)(Xc + ab[((Q_) + 1) * 2 + 0] + ko);            \
      NXT[1] = *(const short8*)(Xc + ab[((Q_) + 1) * 2 + 0] + ko + 1024);     \
      NXT[2] = *(const short8*)(Xc + ab[((Q_) + 1) * 2 + 1] + ko);            \
      NXT[3] = *(const short8*)(Xc + ab[((Q_) + 1) * 2 + 1] + ko + 1024);     \
    } else {         /* stage B(t+2); read A(t+1, q0) -> NXT */               \
      stage_B(t + 2, stg);                                                    \
      FENCE();                                                                \
      int tn = t + 1 < NT ? t + 1 : NT - 1;                                   \
      uint32_t ko = (uint32_t)(2 * tn) << 10;                                 \
      NXT[0] = *(const short8*)(Xc + ab[0] + ko);                             \
      NXT[1] = *(const short8*)(Xc + ab[0] + ko + 1024);                      \
      NXT[2] = *(const short8*)(Xc + ab[1] + ko);                             \
      NXT[3] = *(const short8*)(Xc + ab[1] + ko + 1024);                      \
    }                                                                         \
    __builtin_amdgcn_s_setprio(1);                                            \
    _Pragma("unroll")                                                         \
    for (int n = 0; n < 4; ++n) {                                             \
      acc[2 * (Q_)][n] = __builtin_amdgcn_mfma_f32_16x16x32_bf16(             \
          __builtin_bit_cast(bf16x8, CUR[0]),                                 \
          __builtin_bit_cast(bf16x8, bfr[n][0]), acc[2 * (Q_)][n], 0, 0, 0);  \
      acc[2 * (Q_) + 1][n] = __builtin_amdgcn_mfma_f32_16x16x32_bf16(         \
          __builtin_bit_cast(bf16x8, CUR[2]),                                 \
          __builtin_bit_cast(bf16x8, bfr[n][0]), acc[2 * (Q_) + 1][n], 0, 0,  \
          0);                                                                 \
    }                                                                         \
    _Pragma("unroll")                                                         \
    for (int n = 0; n < 4; ++n) {                                             \
      acc[2 * (Q_)][n] = __builtin_amdgcn_mfma_f32_16x16x32_bf16(             \
          __builtin_bit_cast(bf16x8, CUR[1]),                                 \
          __builtin_bit_cast(bf16x8, bfr[n][1]), acc[2 * (Q_)][n], 0, 0, 0);  \
      acc[2 * (Q_) + 1][n] = __builtin_amdgcn_mfma_f32_16x16x32_bf16(         \
          __builtin_bit_cast(bf16x8, CUR[3]),                                 \
          __builtin_bit_cast(bf16x8, bfr[n][1]), acc[2 * (Q_) + 1][n], 0, 0,  \
          0);                                                                 \
    }                                                                         \
    __builtin_amdgcn_s_setprio(0);                                            \
  }

  for (int t = 0; t < NT; ++t) {
    int pb = bufB * 32768;
    int stg = bufB + 2; if (stg >= 3) stg -= 3;
    // B frags for this tile: one 8-read burst (k0 slices first)
#pragma unroll
    for (int n = 0; n < 4; ++n)
      bfr[n][0] = *(const short8*)(smem + pb + (n * 8 + wc * 2) * 1024 +
                                   (lane << 4));
#pragma unroll
    for (int n = 0; n < 4; ++n)
      bfr[n][1] = *(const short8*)(smem + pb + (n * 8 + wc * 2 + 1) * 1024 +
                                   (lane << 4));
    PHASE(0, arE, arO)
    PHASE(1, arO, arE)
    PHASE(2, arE, arO)
    PHASE(3, arO, arE)
    bufB = bufB + 1; if (bufB >= 3) bufB = 0;
    if (t < NT - 1) {
      VMCNT(24);   // retire B(t+1)'s DMA (24 ops issued after it)
      SBAR();
    }
  }
#undef PHASE

  // ---- fused LSTM epilogue (acc[m][n]: n = gate) ----
  int col = hcol0 + wc * 16 + fr;
  float bi = bias[col], bf_ = bias[1024 + col];
  float bo = bias[2048 + col], bc = bias[3072 + col];
#pragma unroll
  for (int m = 0; m < 8; ++m) {
    int row0 = brow0 + (2 * (m >> 1) + wr) * 32 + (m & 1) * 16 + ((lane >> 4) << 2);
#pragma unroll
    for (int j = 0; j < 4; ++j) {
      size_t idx = (size_t)(row0 + j) * 1024 + col;
      float i_ = fast_sigm(acc[m][0][j] + bi);
      float f_ = fast_sigm(acc[m][1][j] + bf_);
      float o_ = fast_sigm(acc[m][2][j] + bo);
      float ch = fast_tanh(acc[m][3][j] + bc);
      float cn = i_ * ch + f_ * c0[idx];
      out_c[idx] = cn;
      out_h[idx] = o_ * fast_tanh(cn);
    }
  }
}

// Fallback if ws too small (not expected; ws >= 160MB confirmed in round 1).
__global__ __launch_bounds__(256) void lstm_naive(
    const float* __restrict__ y, const float* __restrict__ ctx,
    const float* __restrict__ c0, const float* __restrict__ h0,
    const float* __restrict__ W, const float* __restrict__ U,
    const float* __restrict__ C, const float* __restrict__ b,
    float* __restrict__ out_c, float* __restrict__ out_h) {
  size_t t = (size_t)blockIdx.x * blockDim.x + threadIdx.x;
  if (t >= (size_t)Bn * Hn) return;
  int row = (int)(t >> 10), col = (int)(t & 1023);
  float g[4];
#pragma unroll
  for (int gg = 0; gg < 4; ++gg) {
    int wrow = gg * 1024 + col;
    float s = b[wrow];
    const float* yr = y + (size_t)row * 1024;
    const float* Wr = W + (size_t)wrow * 1024;
    for (int k = 0; k < 1024; ++k) s += yr[k] * Wr[k];
    const float* hr = h0 + (size_t)row * 1024;
    const float* Ur = U + (size_t)wrow * 1024;
    for (int k = 0; k < 1024; ++k) s += hr[k] * Ur[k];
    const float* cr = ctx + (size_t)row * 2048;
    const float* Cr = C + (size_t)wrow * 2048;
    for (int k = 0; k < 2048; ++k) s += cr[k] * Cr[k];
    g[gg] = s;
  }
  float i_ = fast_sigm(g[0]), f_ = fast_sigm(g[1]);
  float o_ = fast_sigm(g[2]), ch = fast_tanh(g[3]);
  float cn = i_ * ch + f_ * c0[t];
  out_c[t] = cn;
  out_h[t] = o_ * fast_tanh(cn);
}

extern "C" void kernel_launch(void* const* d_in, const int* in_sizes, int n_in,
                              void* d_out, int out_size, void* d_ws, size_t ws_size,
                              hipStream_t stream) {
  const float* y   = (const float*)d_in[0];
  const float* ctx = (const float*)d_in[1];
  const float* c0  = (const float*)d_in[2];
  const float* h0  = (const float*)d_in[3];
  const float* W   = (const float*)d_in[4];
  const float* U   = (const float*)d_in[5];
  const float* C   = (const float*)d_in[6];
  const float* b   = (const float*)d_in[7];
  float* out = (float*)d_out;
  float* out_c = out;
  float* out_h = out + (size_t)Bn * Hn;

  const size_t needX = (size_t)Bn * KT * 2;
  const size_t needW = (size_t)(4 * Hn) * KT * 2;

  if (ws_size >= needX + needW) {
    unsigned short* Xb = (unsigned short*)d_ws;
    unsigned short* Wb = (unsigned short*)((char*)d_ws + needX);
    cvt_pack_x<<<2048, 256, 0, stream>>>(y, h0, ctx, Xb,
                                         (long long)Bn * KT / 8);
    cvt_pack_w<<<2048, 256, 0, stream>>>(W, U, C, Wb,
                                         (long long)(4 * Hn) * KT / 8);
    (void)hipFuncSetAttribute((const void*)lstm_gemm,
                              hipFuncAttributeMaxDynamicSharedMemorySize, 98304);
    lstm_gemm<<<1024, 512, 98304, stream>>>(Xb, Wb, b, c0, out_c, out_h);
  } else {
    lstm_naive<<<(Bn * Hn + 255) / 256, 256, 0, stream>>>(y, ctx, c0, h0, W, U, C,
                                                          b, out_c, out_h);
  }
}

// Round 19
// 556.186 us; speedup vs baseline: 1.3554x; 1.3554x over previous
//
#include <hip/hip_runtime.h>
#include <hip/hip_bf16.h>
#include <stdint.h>

typedef __attribute__((ext_vector_type(8))) short short8;
typedef __attribute__((ext_vector_type(8))) unsigned short ushort8;
typedef __attribute__((ext_vector_type(4))) float f32x4;
typedef __attribute__((ext_vector_type(8))) __bf16 bf16x8;

#define GAS __attribute__((address_space(1)))
#define LAS __attribute__((address_space(3)))

static constexpr int Bn = 16384;   // batch
static constexpr int Hn = 1024;    // hidden
static constexpr int KT = 4096;    // IN + H + CTX (concat K)
static constexpr int NT = KT / 64; // 64 K-tiles per generation

#define SBAR()   __builtin_amdgcn_s_barrier()
#define VMCNT(n) asm volatile("s_waitcnt vmcnt(" #n ")" ::: "memory")
#define FENCE()  asm volatile("" ::: "memory")

__device__ __forceinline__ unsigned short f2bf(float f) {
  unsigned u = __builtin_bit_cast(unsigned, f);
  u = (u + 0x7FFFu + ((u >> 16) & 1u)) >> 16;   // RNE
  return (unsigned short)u;
}

__device__ __forceinline__ float fast_sigm(float x) {
  return __builtin_amdgcn_rcpf(1.f + __expf(-x));
}
__device__ __forceinline__ float fast_tanh(float x) {
  return 1.f - 2.f * __builtin_amdgcn_rcpf(__expf(2.f * x) + 1.f);
}

// Concat-convert 3 fp32 sources (widths 1024,1024,2048) into bf16 [rows][4096].
__global__ __launch_bounds__(256) void cvt_concat_k(
    const float* __restrict__ s0, const float* __restrict__ s1,
    const float* __restrict__ s2, unsigned short* __restrict__ dst,
    long long n8) {
  long long stride = (long long)gridDim.x * blockDim.x;
  for (long long g = (long long)blockIdx.x * blockDim.x + threadIdx.x; g < n8;
       g += stride) {
    long long row = g >> 9;
    int cg = (int)(g & 511) << 3;
    const float* src;
    if (cg < 1024)      src = s0 + row * 1024 + cg;
    else if (cg < 2048) src = s1 + row * 1024 + (cg - 1024);
    else                src = s2 + row * 2048 + (cg - 2048);
    float4 f0 = *(const float4*)src;
    float4 f1 = *(const float4*)(src + 4);
    ushort8 o;
    o[0] = f2bf(f0.x); o[1] = f2bf(f0.y); o[2] = f2bf(f0.z); o[3] = f2bf(f0.w);
    o[4] = f2bf(f1.x); o[5] = f2bf(f1.y); o[6] = f2bf(f1.z); o[7] = f2bf(f1.w);
    *(ushort8*)(dst + (g << 3)) = o;
  }
}

// Pack W|U|C into 16x16x32-MFMA B-frag records — WRITE-COALESCED (r10).
__global__ __launch_bounds__(256) void cvt_pack_w(
    const float* __restrict__ s0, const float* __restrict__ s1,
    const float* __restrict__ s2, unsigned short* __restrict__ dst,
    long long ntot) {
  long long stride = (long long)gridDim.x * blockDim.x;
  for (long long g = (long long)blockIdx.x * blockDim.x + threadIdx.x; g < ntot;
       g += stride) {
    int li = (int)(g & 63);
    long long rec = g >> 6;
    int cb = (int)(rec & 255);
    int k32 = (int)(rec >> 8);
    int fr = li & 15, ksl = li >> 4;
    int row = cb * 16 + fr;            // W-concat row = gemm column
    int k0 = k32 * 32 + ksl * 8;
    const float* src;
    if (k0 < 1024)      src = s0 + (size_t)row * 1024 + k0;
    else if (k0 < 2048) src = s1 + (size_t)row * 1024 + (k0 - 1024);
    else                src = s2 + (size_t)row * 2048 + (k0 - 2048);
    float4 f0 = *(const float4*)src;
    float4 f1 = *(const float4*)(src + 4);
    ushort8 o;
    o[0] = f2bf(f0.x); o[1] = f2bf(f0.y); o[2] = f2bf(f0.z); o[3] = f2bf(f0.w);
    o[4] = f2bf(f1.x); o[5] = f2bf(f1.y); o[6] = f2bf(f1.z); o[7] = f2bf(f1.w);
    *(ushort8*)(dst + (g << 3)) = o;
  }
}

// 256x256 GEMM + fused LSTM. 16x16x32 MFMA, 8 waves (2M x 4N).  [r10 core]
// PERSISTENT BLOCKS (r17, best measured): grid=256 (1/CU); each block runs 4
// M-tiles (generations) at the SAME cblk. The r10 K-loop is UNCHANGED per
// tile; tail clamped stages of gen g become the REAL A(0),A(1) of gen g+1,
// and the t=63 B-prefetch naturally targets B(g+1, tile0). Continuous mod-3
// buffer rotation lines up with steady state, so the pipeline never drains
// across generations; B panel (2MB/cblk) stays L2-hot across all 4 gens.
// Ledger within a generation: identical to r10 (12 VMEM/tile: B(t+1)x8 @q1,
// A(t+2)x4 @q3; ONE {VMCNT(12); s_barrier} per tile; never vmcnt(0)).
__global__ __launch_bounds__(512, 2) void lstm_gemm(
    const unsigned short* __restrict__ X, const unsigned short* __restrict__ Wp,
    const float* __restrict__ bias, const float* __restrict__ c0,
    float* __restrict__ out_c, float* __restrict__ out_h) {
  extern __shared__ char smem[];  // 3 x 32KB A buffers

  int bid = blockIdx.x;
  int swz = (bid & 7) * 32 + (bid >> 3);   // 256 blocks, 8 XCDs, bijective
  int cblk = swz >> 4;                     // 0..15 (64 H-cols each)
  int mgroup = swz & 15;                   // 0..15 (4 M-tiles each)
  int hcol0 = cblk * 64;

  int tid = threadIdx.x;
  int lane = tid & 63, wid = tid >> 6;
  int wr = wid >> 2, wc = wid & 3;  // 2M x 4N wave grid

  const char* Xc = (const char*)X;
  const char* Wpc = (const char*)Wp;

  // ---- A staging bases: current gen (aoffj) and next gen (aoffjN) ----
  int rr = tid >> 3;                                        // 0..63
  uint32_t cbyte = (uint32_t)(((tid & 7) * 16) ^ ((rr & 7) << 4));
  uint32_t aoffj[4], aoffjN[4];
#pragma unroll
  for (int j = 0; j < 4; ++j) {
    aoffj[j] = (uint32_t)(mgroup * 1024 + j * 64 + rr) * 8192u + cbyte;
    aoffjN[j] = aoffj[j] + (256u * 8192u);   // +1 generation (256 rows)
  }

  // stage A K-tile ts (0..63) of current (nxt=0) or next (nxt=1) generation
  auto stage_A = [&](int ts, int nxt, int dbuf) {
#pragma unroll
    for (int j = 0; j < 4; ++j) {
      uint32_t off = (nxt ? aoffjN[j] : aoffj[j]) + (uint32_t)ts * 128u;
      const char* src = Xc + off;
      char* dst = smem + dbuf * 32768 + j * 8192 + wid * 1024;
      __builtin_amdgcn_global_load_lds((const GAS unsigned int*)src,
                                       (LAS unsigned int*)dst, 16, 0, 0);
    }
  };

  // ---- A ds_read swizzled offsets ----
  int kg = (lane >> 4) << 4;
  int sw = (lane & 7) << 4;
  int koff0 = kg ^ sw;
  int koff1 = (64 + kg) ^ sw;
  int fr = lane & 15;

  // ---- B frag-major per-lane base pointers (gate n) — cblk-only, all gens --
  const char* bbp[4];
#pragma unroll
  for (int n = 0; n < 4; ++n) {
    int cb = n * 64 + cblk * 4 + wc;
    bbp[n] = Wpc + ((size_t)cb * 64 + lane) * 16;
  }

  f32x4 acc[8][4] = {};
  short8 bfrE[4][2], bfrO[4][2];   // B frag parity sets [n][k-slice]

  // ---- prologue (once): A(g0,0); fence; B(0)->E + A(g0,1) ----
  stage_A(0, 0, 0);
  FENCE();
#pragma unroll
  for (int n = 0; n < 4; ++n) {
    bfrE[n][0] = *(const short8*)(bbp[n]);
    bfrE[n][1] = *(const short8*)(bbp[n] + 262144);
  }
  stage_A(1, 0, 1);

  int bufA = 0;

#define TILE(T_, G_, BC, BN)                                                  \
  {                                                                           \
    VMCNT(12);                                                                \
    SBAR();                                                                   \
    int pb = bufA * 32768;                                                    \
    int stg = bufA + 2; if (stg >= 3) stg -= 3;                               \
    _Pragma("unroll")                                                         \
    for (int q = 0; q < 4; ++q) {                                             \
      int ab = pb + ((2 * q + wr) * 32 + fr) * 128;                           \
      short8 a0 = *(const short8*)(smem + ab + koff0);                        \
      short8 a1 = *(const short8*)(smem + ab + koff1);                        \
      short8 a2 = *(const short8*)(smem + ab + 2048 + koff0);                 \
      short8 a3 = *(const short8*)(smem + ab + 2048 + koff1);                 \
      if (q == 1) {  /* coalesced B prefetch for global tile +1 */            \
        int gt1 = (G_)*NT + (T_) + 1;                                         \
        int tsb = gt1 < 4 * NT ? (gt1 & 63) : 63;                             \
        size_t tb = (size_t)(2 * tsb) * 262144u;                              \
        _Pragma("unroll")                                                     \
        for (int n = 0; n < 4; ++n) {                                         \
          BN[n][0] = *(const short8*)(bbp[n] + tb);                           \
          BN[n][1] = *(const short8*)(bbp[n] + tb + 262144);                  \
        }                                                                     \
      }                                                                       \
      if (q == 3) {  /* stage A tile +2 (rolls into next generation) */       \
        int tp2 = (T_) + 2;                                                   \
        stage_A(tp2 & 63, tp2 >= NT ? 1 : 0, stg);                            \
      }                                                                       \
      __builtin_amdgcn_s_setprio(1);                                          \
      _Pragma("unroll")                                                       \
      for (int n = 0; n < 4; ++n) {                                           \
        acc[2 * q][n] = __builtin_amdgcn_mfma_f32_16x16x32_bf16(              \
            __builtin_bit_cast(bf16x8, a0), __builtin_bit_cast(bf16x8, BC[n][0]),\
            acc[2 * q][n], 0, 0, 0);                                          \
        acc[2 * q + 1][n] = __builtin_amdgcn_mfma_f32_16x16x32_bf16(          \
            __builtin_bit_cast(bf16x8, a2), __builtin_bit_cast(bf16x8, BC[n][0]),\
            acc[2 * q + 1][n], 0, 0, 0);                                      \
      }                                                                       \
      _Pragma("unroll")                                                       \
      for (int n = 0; n < 4; ++n) {                                           \
        acc[2 * q][n] = __builtin_amdgcn_mfma_f32_16x16x32_bf16(              \
            __builtin_bit_cast(bf16x8, a1), __builtin_bit_cast(bf16x8, BC[n][1]),\
            acc[2 * q][n], 0, 0, 0);                                          \
        acc[2 * q + 1][n] = __builtin_amdgcn_mfma_f32_16x16x32_bf16(          \
            __builtin_bit_cast(bf16x8, a3), __builtin_bit_cast(bf16x8, BC[n][1]),\
            acc[2 * q + 1][n], 0, 0, 0);                                      \
      }                                                                       \
      __builtin_amdgcn_s_setprio(0);                                          \
    }                                                                         \
    bufA = bufA + 1; if (bufA >= 3) bufA = 0;                                 \
  }

  for (int g = 0; g < 4; ++g) {
    for (int t = 0; t < NT; t += 2) {
      TILE(t, g, bfrE, bfrO)
      TILE(t + 1, g, bfrO, bfrE)
    }

    // ---- fused LSTM epilogue for this generation (c0/out from global;
    //      next-gen A/B staging already in flight underneath) ----
    int brow0 = (mgroup * 4 + g) * 256;
    int col = hcol0 + wc * 16 + fr;
    float bi = bias[col], bf_ = bias[1024 + col];
    float bo = bias[2048 + col], bc = bias[3072 + col];
#pragma unroll
    for (int m = 0; m < 8; ++m) {
      int row0 =
          brow0 + (2 * (m >> 1) + wr) * 32 + (m & 1) * 16 + ((lane >> 4) << 2);
#pragma unroll
      for (int j = 0; j < 4; ++j) {
        size_t idx = (size_t)(row0 + j) * 1024 + col;
        float i_ = fast_sigm(acc[m][0][j] + bi);
        float f_ = fast_sigm(acc[m][1][j] + bf_);
        float o_ = fast_sigm(acc[m][2][j] + bo);
        float ch = fast_tanh(acc[m][3][j] + bc);
        float cn = i_ * ch + f_ * c0[idx];
        out_c[idx] = cn;
        out_h[idx] = o_ * fast_tanh(cn);
      }
    }

    // reset accumulators (element-wise: static indices, stays in AGPRs)
#pragma unroll
    for (int m = 0; m < 8; ++m)
#pragma unroll
      for (int n = 0; n < 4; ++n)
#pragma unroll
        for (int j = 0; j < 4; ++j) acc[m][n][j] = 0.f;

    // advance generation bases: aoffj <- aoffjN; aoffjN <- gen+2 (clamped)
#pragma unroll
    for (int j = 0; j < 4; ++j) {
      aoffj[j] = aoffjN[j];
      if (g < 2) aoffjN[j] += 256u * 8192u;
    }
  }
#undef TILE
}

// Fallback if ws too small (not expected; ws >= 160MB confirmed in round 1).
__global__ __launch_bounds__(256) void lstm_naive(
    const float* __restrict__ y, const float* __restrict__ ctx,
    const float* __restrict__ c0, const float* __restrict__ h0,
    const float* __restrict__ W, const float* __restrict__ U,
    const float* __restrict__ C, const float* __restrict__ b,
    float* __restrict__ out_c, float* __restrict__ out_h) {
  size_t t = (size_t)blockIdx.x * blockDim.x + threadIdx.x;
  if (t >= (size_t)Bn * Hn) return;
  int row = (int)(t >> 10), col = (int)(t & 1023);
  float g[4];
#pragma unroll
  for (int gg = 0; gg < 4; ++gg) {
    int wrow = gg * 1024 + col;
    float s = b[wrow];
    const float* yr = y + (size_t)row * 1024;
    const float* Wr = W + (size_t)wrow * 1024;
    for (int k = 0; k < 1024; ++k) s += yr[k] * Wr[k];
    const float* hr = h0 + (size_t)row * 1024;
    const float* Ur = U + (size_t)wrow * 1024;
    for (int k = 0; k < 1024; ++k) s += hr[k] * Ur[k];
    const float* cr = ctx + (size_t)row * 2048;
    const float* Cr = C + (size_t)wrow * 2048;
    for (int k = 0; k < 2048; ++k) s += cr[k] * Cr[k];
    g[gg] = s;
  }
  float i_ = fast_sigm(g[0]), f_ = fast_sigm(g[1]);
  float o_ = fast_sigm(g[2]), ch = fast_tanh(g[3]);
  float cn = i_ * ch + f_ * c0[t];
  out_c[t] = cn;
  out_h[t] = o_ * fast_tanh(cn);
}

extern "C" void kernel_launch(void* const* d_in, const int* in_sizes, int n_in,
                              void* d_out, int out_size, void* d_ws, size_t ws_size,
                              hipStream_t stream) {
  const float* y   = (const float*)d_in[0];
  const float* ctx = (const float*)d_in[1];
  const float* c0  = (const float*)d_in[2];
  const float* h0  = (const float*)d_in[3];
  const float* W   = (const float*)d_in[4];
  const float* U   = (const float*)d_in[5];
  const float* C   = (const float*)d_in[6];
  const float* b   = (const float*)d_in[7];
  float* out = (float*)d_out;
  float* out_c = out;
  float* out_h = out + (size_t)Bn * Hn;

  const size_t needX = (size_t)Bn * KT * 2;
  const size_t needW = (size_t)(4 * Hn) * KT * 2;

  if (ws_size >= needX + needW) {
    unsigned short* Xb = (unsigned short*)d_ws;
    unsigned short* Wb = (unsigned short*)((char*)d_ws + needX);
    cvt_concat_k<<<2048, 256, 0, stream>>>(y, h0, ctx, Xb, (long long)Bn * 512);
    cvt_pack_w<<<2048, 256, 0, stream>>>(W, U, C, Wb,
                                         (long long)(4 * Hn) * KT / 8);
    (void)hipFuncSetAttribute((const void*)lstm_gemm,
                              hipFuncAttributeMaxDynamicSharedMemorySize, 98304);
    lstm_gemm<<<256, 512, 98304, stream>>>(Xb, Wb, b, c0, out_c, out_h);
  } else {
    lstm_naive<<<(Bn * Hn + 255) / 256, 256, 0, stream>>>(y, ctx, c0, h0, W, U, C,
                                                          b, out_c, out_h);
  }
}